// Round 7
// baseline (178.197 us; speedup 1.0000x reference)
//
#include <hip/hip_runtime.h>

// ProtoNet loss pipeline on MI355X (gfx950) — round 7.
// C=256 classes, S=5 support, Q=64 queries, D_IN=1024, Z=128.
//
// Round-7: k_gemm_z redesigned FOR the compiler's 64-VGPR max-occupancy cap
// (observed every round: VGPR_Count 60-64, loads serialized at ~400cyc, MLP=1).
// Instead of fighting it with prefetch registers, embrace it: tiny per-wave
// footprint (acc[2] = 8 VGPRs, ~40 live total) so 8 waves/SIMD are resident
// and raw TLP hides the serialized load latency (Little's law: 8 waves /
// 400cyc = 1 load per 50cyc per SIMD -> ~11us for the whole GEMM).
//  - Block = 16 rows x 128 cols; wave w owns cols w*32..+31, FULL K=1024.
//    No K-split -> no LDS combine, no in-loop barriers, no prefetch regs.
//  - 1040 blocks x 256 thr = 4160 waves, self-balancing across 1024 SIMDs.
// k_d2red: B-loads batched 4-ahead per t-tile (MLP 4). k_prep unchanged.

typedef __attribute__((ext_vector_type(8))) short s8v;
typedef __attribute__((ext_vector_type(4))) float f32x4;

__device__ __forceinline__ short f2bf(float f) {
  union { float f; unsigned u; } v; v.f = f;
  unsigned r = (v.u + 0x7fffu + ((v.u >> 16) & 1u)) >> 16;   // RNE
  return (short)r;
}

// blocks 0..255: xbar[c,:] = mean_s xs[c,s,:]; block 0 also zeroes out[0..1].
// blocks 256..271: Wt[n][k] = bf16(W[k][n]) via LDS transpose (64 k-rows each).
__global__ __launch_bounds__(256) void k_prep(
    const float* __restrict__ xs, const float* __restrict__ W,
    float* __restrict__ xbar, unsigned short* __restrict__ Wt,
    float* __restrict__ out) {
  __shared__ unsigned short T[128 * 68];
  const int tid = threadIdx.x;
  if (blockIdx.x < 256) {
    const int c = blockIdx.x;
    if (c == 0 && tid < 2) out[tid] = 0.0f;
    const float* b = xs + (size_t)c * 5120;
    for (int e = tid; e < 1024; e += 256) {
      float s = b[e] + b[1024 + e] + b[2048 + e] + b[3072 + e] + b[4096 + e];
      xbar[(size_t)c * 1024 + e] = s * 0.2f;
    }
  } else {
    const int kb = (blockIdx.x - 256) * 64;
#pragma unroll
    for (int s = 0; s < 8; ++s) {          // 2048 float4 = 64 k x 32 n4
      int idx = tid + s * 256;
      int kr = idx >> 5, n4 = idx & 31;
      float4 v = *(const float4*)(W + (size_t)(kb + kr) * 128 + n4 * 4);
      T[(n4 * 4 + 0) * 68 + kr] = (unsigned short)f2bf(v.x);
      T[(n4 * 4 + 1) * 68 + kr] = (unsigned short)f2bf(v.y);
      T[(n4 * 4 + 2) * 68 + kr] = (unsigned short)f2bf(v.z);
      T[(n4 * 4 + 3) * 68 + kr] = (unsigned short)f2bf(v.w);
    }
    __syncthreads();
#pragma unroll
    for (int s = 0; s < 8; ++s) {          // 2048 ushort4 = 128 n x 16 k4
      int idx = tid + s * 256;
      int n = idx >> 4, k4 = idx & 15;
      ushort4 o;
      o.x = T[n * 68 + k4 * 4 + 0];
      o.y = T[n * 68 + k4 * 4 + 1];
      o.z = T[n * 68 + k4 * 4 + 2];
      o.w = T[n * 68 + k4 * 4 + 3];
      *(ushort4*)(Wt + (size_t)n * 1024 + kb + k4 * 4) = o;
    }
  }
}

// ---------------- z = [xbar ; xq] @ W,  M=16640 N=128 K=1024 ----------------
// 1040 blocks x 256 threads. Block = rows rb..rb+15; wave w = cols w*32..+31,
// full K. acc[2] only; no barriers in the K-loop; TLP is the latency-hider.
__global__ __launch_bounds__(256) void k_gemm_z(
    const float* __restrict__ xbar, const float* __restrict__ xq,
    const unsigned short* __restrict__ Wt,
    unsigned short* __restrict__ zb, float* __restrict__ n2) {
  __shared__ float P[4][16];               // per-wave n2 partials
  const int tid = threadIdx.x;
  const int w = tid >> 6, l = tid & 63, ln = l & 15, qd = l >> 4;
  const int rb = blockIdx.x * 16;
  const float* abase = (rb < 256) ? (xbar + (size_t)rb * 1024)
                                  : (xq + (size_t)(rb - 256) * 1024);
  const float* arow = abase + (size_t)ln * 1024 + qd * 8;
  const unsigned short* b0p = Wt + (size_t)(w * 32 + ln) * 1024 + qd * 8;
  const unsigned short* b1p = b0p + 16 * 1024;

  f32x4 acc0 = {}, acc1 = {};
#pragma unroll 4
  for (int kt = 0; kt < 32; ++kt) {
    float4 a0 = *(const float4*)(arow + kt * 32);
    float4 a1 = *(const float4*)(arow + kt * 32 + 4);
    s8v b0 = *(const s8v*)(b0p + kt * 32);
    s8v b1 = *(const s8v*)(b1p + kt * 32);
    s8v af = { f2bf(a0.x), f2bf(a0.y), f2bf(a0.z), f2bf(a0.w),
               f2bf(a1.x), f2bf(a1.y), f2bf(a1.z), f2bf(a1.w) };
    acc0 = __builtin_amdgcn_mfma_f32_16x16x32_bf16(af, b0, acc0, 0, 0, 0);
    acc1 = __builtin_amdgcn_mfma_f32_16x16x32_bf16(af, b1, acc1, 0, 0, 0);
  }
  // epilogue: bf16 z stores + per-row n2 partials (this wave's 32 cols)
#pragma unroll
  for (int p = 0; p < 4; ++p) {
    const int grow = rb + qd * 4 + p;      // C/D: row = quad*4 + reg
    float v0 = acc0[p], v1 = acc1[p];      // cols w*32+ln, w*32+16+ln
    zb[(size_t)grow * 128 + w * 32 + ln] = (unsigned short)f2bf(v0);
    zb[(size_t)grow * 128 + w * 32 + 16 + ln] = (unsigned short)f2bf(v1);
    float sp = v0 * v0 + v1 * v1;
    sp += __shfl_xor(sp, 1);
    sp += __shfl_xor(sp, 2);
    sp += __shfl_xor(sp, 4);
    sp += __shfl_xor(sp, 8);
    if (ln == 0) P[w][qd * 4 + p] = sp;
  }
  __syncthreads();
  if (tid < 16)
    n2[rb + tid] = P[0][tid] + P[1][tid] + P[2][tid] + P[3][tid];
}

// --------- fused d2 GEMM (64 queries x 256 protos) + per-class reduce ---------
__global__ __launch_bounds__(256, 1) void k_d2red(
    const unsigned short* __restrict__ zb, const float* __restrict__ n2,
    float* __restrict__ out) {
  __shared__ float Dt[256 * 65];          // Dt[j][q], stride 65 (bank-free)
  __shared__ float rv[256];
  __shared__ int   ri[256];
  __shared__ float rss[256];
  __shared__ float invn[64];
  __shared__ float sred[4];
  __shared__ float s_tc, s_aq2, s_corr;
  const int tid = threadIdx.x;
  const int c = blockIdx.x;
  const int w = tid >> 6, lane = tid & 63, ln = lane & 15, qd = lane >> 4;

  // d2 tile via MFMA: wave w handles query rows c*64 + w*16 .. +15
  f32x4 acc[16] = {};
  const unsigned short* Az = zb + (size_t)(256 + c * 64 + w * 16 + ln) * 128;
  s8v af[4];
#pragma unroll
  for (int kt = 0; kt < 4; ++kt) af[kt] = *(const s8v*)(Az + kt * 32 + qd * 8);
#pragma unroll
  for (int t = 0; t < 16; ++t) {
    const unsigned short* Bz = zb + (size_t)(t * 16 + ln) * 128 + qd * 8;
    s8v bf0 = *(const s8v*)(Bz + 0 * 32);
    s8v bf1 = *(const s8v*)(Bz + 1 * 32);
    s8v bf2 = *(const s8v*)(Bz + 2 * 32);
    s8v bf3 = *(const s8v*)(Bz + 3 * 32);
    acc[t] = __builtin_amdgcn_mfma_f32_16x16x32_bf16(af[0], bf0, acc[t], 0, 0, 0);
    acc[t] = __builtin_amdgcn_mfma_f32_16x16x32_bf16(af[1], bf1, acc[t], 0, 0, 0);
    acc[t] = __builtin_amdgcn_mfma_f32_16x16x32_bf16(af[2], bf2, acc[t], 0, 0, 0);
    acc[t] = __builtin_amdgcn_mfma_f32_16x16x32_bf16(af[3], bf3, acc[t], 0, 0, 0);
  }
#pragma unroll
  for (int p = 0; p < 4; ++p) {
    int qloc = w * 16 + qd * 4 + p;
    float qn = n2[256 + c * 64 + qloc];
#pragma unroll
    for (int t = 0; t < 16; ++t) {
      int j = t * 16 + ln;
      Dt[j * 65 + qloc] = qn + n2[j] - 2.0f * acc[t][p];
    }
  }
  __syncthreads();

  // per-row (query) stats: thread tid handles row q=tid&63, j-quarter (tid>>6)
  {
    const int q = tid & 63, jb = (tid >> 6) * 64;
    float mn = 3.4e38f; int mi = 0; float ss = 0.0f;
    for (int jj = 0; jj < 64; ++jj) {
      int j = jb + jj;
      float f = Dt[j * 65 + q];
      ss += f * f;
      if (f < mn) { mn = f; mi = j; }
    }
    rv[tid] = mn; ri[tid] = mi; rss[tid] = ss;
  }
  __syncthreads();
  if (tid < 64) {   // combine quarters; ascending h + strict < => first-occurrence
    float bm = rv[tid]; int bi = ri[tid]; float ss = rss[tid];
    for (int hh = 1; hh < 4; ++hh) {
      float v = rv[hh * 64 + tid];
      ss += rss[hh * 64 + tid];
      if (v < bm) { bm = v; bi = ri[hh * 64 + tid]; }
    }
    float col = Dt[c * 65 + tid];
    float loo2 = fmaxf(ss - col * col, 0.0f);
    float nrm = fmaxf(sqrtf(loo2), 1e-8f);
    float inv = 1.0f / nrm;
    invn[tid] = inv;
    float aq2 = loo2 * inv * inv;          // ||a_q||^2
    float corr = (bi == c) ? 1.0f : 0.0f;
    for (int m = 1; m < 64; m <<= 1) {
      aq2 += __shfl_xor(aq2, m);
      corr += __shfl_xor(corr, m);
    }
    if (tid == 0) { s_aq2 = aq2; s_corr = corr; }
  }
  __syncthreads();
  // t[j] = sum_q D[q][j] * invn[q]; thread tid = j
  float t = 0.0f;
  for (int qq = 0; qq < 64; ++qq) t += Dt[tid * 65 + qq] * invn[qq];
  if (tid == c) s_tc = t;
  float t2 = t * t;
  for (int m = 1; m < 64; m <<= 1) t2 += __shfl_xor(t2, m);
  if ((tid & 63) == 0) sred[tid >> 6] = t2;
  __syncthreads();
  if (tid == 0) {
    float S2 = sred[0] + sred[1] + sred[2] + sred[3];
    float bs = 0.5f * (S2 - s_tc * s_tc - s_aq2);   // sum_{q<k} sim
    atomicAdd(&out[0], bs * (1.0f / 516096.0f));    // / (C * Q*(Q-1)/2)
    atomicAdd(&out[1], s_corr * (1.0f / 16384.0f)); // / (C*Q)
  }
}

extern "C" void kernel_launch(void* const* d_in, const int* in_sizes, int n_in,
                              void* d_out, int out_size, void* d_ws, size_t ws_size,
                              hipStream_t stream) {
  const float* xs = (const float*)d_in[0];   // 256*5*1024
  const float* xq = (const float*)d_in[1];   // 256*64*1024
  const float* W  = (const float*)d_in[2];   // 1024*128
  float* out = (float*)d_out;

  float* ws = (float*)d_ws;
  float* xbar = ws;                                    // 262144 fp32 (1 MB)
  unsigned short* Wt = (unsigned short*)(xbar + 262144);          // 128K bf16
  unsigned short* zb = Wt + 131072;                               // 16640*128 bf16
  float* n2 = (float*)(zb + (size_t)16640 * 128);                 // 16640 fp32

  k_prep<<<dim3(272), dim3(256), 0, stream>>>(xs, W, xbar, Wt, out);
  k_gemm_z<<<dim3(1040), dim3(256), 0, stream>>>(xbar, xq, Wt, zb, n2);
  k_d2red<<<dim3(256), dim3(256), 0, stream>>>(zb, n2, out);
}

// Round 8
// 147.731 us; speedup vs baseline: 1.2062x; 1.2062x over previous
//
#include <hip/hip_runtime.h>
#include <stdint.h>

// ProtoNet loss pipeline on MI355X (gfx950) — round 8.
// C=256, S=5, Q=64, D_IN=1024, Z=128.
//
// Round-8: k_gemm_z rebuilt on __builtin_amdgcn_global_load_lds (async
// global->LDS DMA, no VGPR result -> compiler issues all 12 staging loads
// back-to-back; one vmcnt drain per K-tile instead of 12x400cyc serialized
// loads — the R2-R7 disease). m97-style 2-barrier K-loop.
//  - Block = 64 rows x 64 cols, full K, BK=128. Grid 520 = 260 M x 2 N.
//    48 KB LDS -> 2 blocks/CU resident; their barriers desync, so one
//    block computes through the other's drain.
//  - LDS layout: 1 KB fragment-major regions; HW placement (uniform base +
//    lane*16) == conflict-free ds_read_b128 fragment layout by construction.
//  - A staged as fp32 (raw copy), converted to bf16 in-register post-ds_read.
//  - n2 row norms: block computes 64-col partial, atomicAdd (n2 zeroed in
//    k_prep; kernel boundary orders it before d2red).
// k_prep (+n2 zero), k_d2red unchanged.

typedef __attribute__((ext_vector_type(8))) short s8v;
typedef __attribute__((ext_vector_type(4))) float f32x4;

__device__ __forceinline__ short f2bf(float f) {
  union { float f; unsigned u; } v; v.f = f;
  unsigned r = (v.u + 0x7fffu + ((v.u >> 16) & 1u)) >> 16;   // RNE
  return (short)r;
}

// Async 16B/lane global->LDS. LDS arg must be the WAVE-UNIFORM base; HW
// deposits lane l at base + l*16. Global arg is per-lane. AS casts via
// integer round-trip (generic LDS pointer's low 32 bits == LDS offset).
__device__ __forceinline__ void async16(const void* g, void* s) {
  typedef __attribute__((address_space(3))) uint32_t lds_t;
  typedef const __attribute__((address_space(1))) uint32_t glb_t;
  __builtin_amdgcn_global_load_lds((glb_t*)(uintptr_t)g,
                                   (lds_t*)(uint32_t)(uintptr_t)s, 16, 0, 0);
}

// blocks 0..255: xbar + zero n2 slice (+ block 0 zeroes out).
// blocks 256..271: Wt[n][k] = bf16(W[k][n]) via LDS transpose.
__global__ __launch_bounds__(256) void k_prep(
    const float* __restrict__ xs, const float* __restrict__ W,
    float* __restrict__ xbar, unsigned short* __restrict__ Wt,
    float* __restrict__ n2, float* __restrict__ out) {
  __shared__ unsigned short T[128 * 68];
  const int tid = threadIdx.x;
  if (blockIdx.x < 256) {
    const int c = blockIdx.x;
    if (c == 0 && tid < 2) out[tid] = 0.0f;
    if (tid < 65) n2[c * 65 + tid] = 0.0f;   // 256*65 = 16640
    const float* b = xs + (size_t)c * 5120;
    for (int e = tid; e < 1024; e += 256) {
      float s = b[e] + b[1024 + e] + b[2048 + e] + b[3072 + e] + b[4096 + e];
      xbar[(size_t)c * 1024 + e] = s * 0.2f;
    }
  } else {
    const int kb = (blockIdx.x - 256) * 64;
#pragma unroll
    for (int s = 0; s < 8; ++s) {
      int idx = tid + s * 256;
      int kr = idx >> 5, n4 = idx & 31;
      float4 v = *(const float4*)(W + (size_t)(kb + kr) * 128 + n4 * 4);
      T[(n4 * 4 + 0) * 68 + kr] = (unsigned short)f2bf(v.x);
      T[(n4 * 4 + 1) * 68 + kr] = (unsigned short)f2bf(v.y);
      T[(n4 * 4 + 2) * 68 + kr] = (unsigned short)f2bf(v.z);
      T[(n4 * 4 + 3) * 68 + kr] = (unsigned short)f2bf(v.w);
    }
    __syncthreads();
#pragma unroll
    for (int s = 0; s < 8; ++s) {
      int idx = tid + s * 256;
      int n = idx >> 4, k4 = idx & 15;
      ushort4 o;
      o.x = T[n * 68 + k4 * 4 + 0];
      o.y = T[n * 68 + k4 * 4 + 1];
      o.z = T[n * 68 + k4 * 4 + 2];
      o.w = T[n * 68 + k4 * 4 + 3];
      *(ushort4*)(Wt + (size_t)n * 1024 + kb + k4 * 4) = o;
    }
  }
}

// ---------------- z = [xbar ; xq] @ W,  M=16640 N=128 K=1024 ----------------
// 520 blocks x 256 thr: blockIdx>>1 = M-tile (64 rows), blockIdx&1 = N-half
// (64 cols). Wave w owns rows w*16..+15 x all 64 cols, full K, BK=128.
// LDS: A 32 regions x 1KB (fp32), B 16 regions x 1KB (bf16).
//   A region ar: e=ar&1, ks=(ar>>1)&3, rg=ar>>3; lane l=(qd,ln) holds
//     row rg*16+ln, floats ks*32+qd*8+e*4 .. +4   (frag read: 2x b128 @ l*16)
//   B region br: ks=br&3, t=br>>2; lane l holds col t*16+ln, bf16 ks*32+qd*8..
__global__ __launch_bounds__(256, 2) void k_gemm_z(
    const float* __restrict__ xbar, const float* __restrict__ xq,
    const unsigned short* __restrict__ Wt,
    unsigned short* __restrict__ zb, float* __restrict__ n2) {
  __shared__ __align__(16) char SM[49152];   // A @0 (32KB), B @32768 (16KB)
  const int tid = threadIdx.x;
  const int w = tid >> 6, l = tid & 63, ln = l & 15, qd = l >> 4;
  const int mb = (blockIdx.x >> 1) * 64;
  const int nb = (blockIdx.x & 1) * 64;
  const float* abase = (mb < 256) ? (xbar + (size_t)mb * 1024)
                                  : (xq + (size_t)(mb - 256) * 1024);
  // per-wave staging sources (wave w stages A regions w*8..+8, B w*4..+4)
  const float* asrc[8];
#pragma unroll
  for (int i = 0; i < 8; ++i) {
    int ar = w * 8 + i;
    int e = ar & 1, ks = (ar >> 1) & 3, rg = ar >> 3;
    asrc[i] = abase + (size_t)(rg * 16 + ln) * 1024 + ks * 32 + qd * 8 + e * 4;
  }
  const unsigned short* bsrc[4];
#pragma unroll
  for (int i = 0; i < 4; ++i) {
    int br = w * 4 + i;
    int ks = br & 3, t = br >> 2;
    bsrc[i] = Wt + (size_t)(nb + t * 16 + ln) * 1024 + ks * 32 + qd * 8;
  }

  f32x4 acc[4] = {};
  for (int kt = 0; kt < 8; ++kt) {
    // stage tile kt (async, no VGPR results)
#pragma unroll
    for (int i = 0; i < 8; ++i)
      async16(asrc[i] + kt * 128, SM + (w * 8 + i) * 1024);
#pragma unroll
    for (int i = 0; i < 4; ++i)
      async16(bsrc[i] + kt * 128, SM + 32768 + (w * 4 + i) * 1024);
    __syncthreads();                       // drains vmcnt -> tile ready
#pragma unroll
    for (int ks = 0; ks < 4; ++ks) {
      f32x4 alo = *(const f32x4*)(SM + (w * 8 + ks * 2 + 0) * 1024 + l * 16);
      f32x4 ahi = *(const f32x4*)(SM + (w * 8 + ks * 2 + 1) * 1024 + l * 16);
      s8v af = { f2bf(alo[0]), f2bf(alo[1]), f2bf(alo[2]), f2bf(alo[3]),
                 f2bf(ahi[0]), f2bf(ahi[1]), f2bf(ahi[2]), f2bf(ahi[3]) };
#pragma unroll
      for (int t = 0; t < 4; ++t) {
        s8v bf = *(const s8v*)(SM + 32768 + (t * 4 + ks) * 1024 + l * 16);
        acc[t] = __builtin_amdgcn_mfma_f32_16x16x32_bf16(af, bf, acc[t], 0, 0, 0);
      }
    }
    __syncthreads();                       // reads done before next stage
  }
  // epilogue: bf16 z + 64-col n2 partial via atomicAdd
#pragma unroll
  for (int p = 0; p < 4; ++p) {
    const int grow = mb + w * 16 + qd * 4 + p;   // C/D: row = quad*4 + reg
    float sp = 0.0f;
#pragma unroll
    for (int t = 0; t < 4; ++t) {
      float v = acc[t][p];                       // col = nb + t*16 + ln
      zb[(size_t)grow * 128 + nb + t * 16 + ln] = (unsigned short)f2bf(v);
      sp += v * v;
    }
    sp += __shfl_xor(sp, 1);
    sp += __shfl_xor(sp, 2);
    sp += __shfl_xor(sp, 4);
    sp += __shfl_xor(sp, 8);
    if (ln == 0) atomicAdd(&n2[grow], sp);
  }
}

// --------- fused d2 GEMM (64 queries x 256 protos) + per-class reduce ---------
__global__ __launch_bounds__(256, 1) void k_d2red(
    const unsigned short* __restrict__ zb, const float* __restrict__ n2,
    float* __restrict__ out) {
  __shared__ float Dt[256 * 65];          // Dt[j][q], stride 65 (bank-free)
  __shared__ float rv[256];
  __shared__ int   ri[256];
  __shared__ float rss[256];
  __shared__ float invn[64];
  __shared__ float sred[4];
  __shared__ float s_tc, s_aq2, s_corr;
  const int tid = threadIdx.x;
  const int c = blockIdx.x;
  const int w = tid >> 6, lane = tid & 63, ln = lane & 15, qd = lane >> 4;

  f32x4 acc[16] = {};
  const unsigned short* Az = zb + (size_t)(256 + c * 64 + w * 16 + ln) * 128;
  s8v af[4];
#pragma unroll
  for (int kt = 0; kt < 4; ++kt) af[kt] = *(const s8v*)(Az + kt * 32 + qd * 8);
#pragma unroll
  for (int t = 0; t < 16; ++t) {
    const unsigned short* Bz = zb + (size_t)(t * 16 + ln) * 128 + qd * 8;
    s8v bf0 = *(const s8v*)(Bz + 0 * 32);
    s8v bf1 = *(const s8v*)(Bz + 1 * 32);
    s8v bf2 = *(const s8v*)(Bz + 2 * 32);
    s8v bf3 = *(const s8v*)(Bz + 3 * 32);
    acc[t] = __builtin_amdgcn_mfma_f32_16x16x32_bf16(af[0], bf0, acc[t], 0, 0, 0);
    acc[t] = __builtin_amdgcn_mfma_f32_16x16x32_bf16(af[1], bf1, acc[t], 0, 0, 0);
    acc[t] = __builtin_amdgcn_mfma_f32_16x16x32_bf16(af[2], bf2, acc[t], 0, 0, 0);
    acc[t] = __builtin_amdgcn_mfma_f32_16x16x32_bf16(af[3], bf3, acc[t], 0, 0, 0);
  }
#pragma unroll
  for (int p = 0; p < 4; ++p) {
    int qloc = w * 16 + qd * 4 + p;
    float qn = n2[256 + c * 64 + qloc];
#pragma unroll
    for (int t = 0; t < 16; ++t) {
      int j = t * 16 + ln;
      Dt[j * 65 + qloc] = qn + n2[j] - 2.0f * acc[t][p];
    }
  }
  __syncthreads();

  {
    const int q = tid & 63, jb = (tid >> 6) * 64;
    float mn = 3.4e38f; int mi = 0; float ss = 0.0f;
    for (int jj = 0; jj < 64; ++jj) {
      int j = jb + jj;
      float f = Dt[j * 65 + q];
      ss += f * f;
      if (f < mn) { mn = f; mi = j; }
    }
    rv[tid] = mn; ri[tid] = mi; rss[tid] = ss;
  }
  __syncthreads();
  if (tid < 64) {
    float bm = rv[tid]; int bi = ri[tid]; float ss = rss[tid];
    for (int hh = 1; hh < 4; ++hh) {
      float v = rv[hh * 64 + tid];
      ss += rss[hh * 64 + tid];
      if (v < bm) { bm = v; bi = ri[hh * 64 + tid]; }
    }
    float col = Dt[c * 65 + tid];
    float loo2 = fmaxf(ss - col * col, 0.0f);
    float nrm = fmaxf(sqrtf(loo2), 1e-8f);
    float inv = 1.0f / nrm;
    invn[tid] = inv;
    float aq2 = loo2 * inv * inv;
    float corr = (bi == c) ? 1.0f : 0.0f;
    for (int m = 1; m < 64; m <<= 1) {
      aq2 += __shfl_xor(aq2, m);
      corr += __shfl_xor(corr, m);
    }
    if (tid == 0) { s_aq2 = aq2; s_corr = corr; }
  }
  __syncthreads();
  float t = 0.0f;
  for (int qq = 0; qq < 64; ++qq) t += Dt[tid * 65 + qq] * invn[qq];
  if (tid == c) s_tc = t;
  float t2 = t * t;
  for (int m = 1; m < 64; m <<= 1) t2 += __shfl_xor(t2, m);
  if ((tid & 63) == 0) sred[tid >> 6] = t2;
  __syncthreads();
  if (tid == 0) {
    float S2 = sred[0] + sred[1] + sred[2] + sred[3];
    float bs = 0.5f * (S2 - s_tc * s_tc - s_aq2);
    atomicAdd(&out[0], bs * (1.0f / 516096.0f));
    atomicAdd(&out[1], s_corr * (1.0f / 16384.0f));
  }
}

extern "C" void kernel_launch(void* const* d_in, const int* in_sizes, int n_in,
                              void* d_out, int out_size, void* d_ws, size_t ws_size,
                              hipStream_t stream) {
  const float* xs = (const float*)d_in[0];   // 256*5*1024
  const float* xq = (const float*)d_in[1];   // 256*64*1024
  const float* W  = (const float*)d_in[2];   // 1024*128
  float* out = (float*)d_out;

  float* ws = (float*)d_ws;
  float* xbar = ws;                                    // 262144 fp32 (1 MB)
  unsigned short* Wt = (unsigned short*)(xbar + 262144);          // 128K bf16
  unsigned short* zb = Wt + 131072;                               // 16640*128 bf16
  float* n2 = (float*)(zb + (size_t)16640 * 128);                 // 16640 fp32

  k_prep<<<dim3(272), dim3(256), 0, stream>>>(xs, W, xbar, Wt, n2, out);
  k_gemm_z<<<dim3(520), dim3(256), 0, stream>>>(xbar, xq, Wt, zb, n2);
  k_d2red<<<dim3(256), dim3(256), 0, stream>>>(zb, n2, out);
}

// Round 9
// 139.202 us; speedup vs baseline: 1.2801x; 1.0613x over previous
//
#include <hip/hip_runtime.h>
#include <stdint.h>

// ProtoNet loss pipeline on MI355X (gfx950) — round 9.
// C=256, S=5, Q=64, D_IN=1024, Z=128.
//
// Round-9: k_gemm_z = round-8 async global_load_lds staging, restructured:
//  - NO N-split: block = 64 rows x 128 cols (A read once; R8's FETCH was 2x).
//  - Double-buffered LDS, BK=64 (2 x [A 16KB fp32 | B 16KB bf16] = 64 KB).
//    Per iter: [syncthreads drains tile kt (issued LAST iter, latency
//    overlapped with compute kt-1)] -> [issue kt+1 into buf^1] -> [compute
//    kt from buf]. One barrier/tile; kt+1 loads fly during compute(kt).
//  - n2 = full-row sum in-block -> plain store (no atomics / pre-zero).
// k_prep, k_d2red unchanged.

typedef __attribute__((ext_vector_type(8))) short s8v;
typedef __attribute__((ext_vector_type(4))) float f32x4;

__device__ __forceinline__ short f2bf(float f) {
  union { float f; unsigned u; } v; v.f = f;
  unsigned r = (v.u + 0x7fffu + ((v.u >> 16) & 1u)) >> 16;   // RNE
  return (short)r;
}

// Async 16B/lane global->LDS. LDS arg = WAVE-UNIFORM base; HW deposits lane
// l at base + l*16. Global arg is per-lane.
__device__ __forceinline__ void async16(const void* g, void* s) {
  typedef __attribute__((address_space(3))) uint32_t lds_t;
  typedef const __attribute__((address_space(1))) uint32_t glb_t;
  __builtin_amdgcn_global_load_lds((glb_t*)(uintptr_t)g,
                                   (lds_t*)(uint32_t)(uintptr_t)s, 16, 0, 0);
}

// blocks 0..255: xbar[c,:] = mean_s xs[c,s,:] (+ block 0 zeroes out).
// blocks 256..271: Wt[n][k] = bf16(W[k][n]) via LDS transpose.
__global__ __launch_bounds__(256) void k_prep(
    const float* __restrict__ xs, const float* __restrict__ W,
    float* __restrict__ xbar, unsigned short* __restrict__ Wt,
    float* __restrict__ out) {
  __shared__ unsigned short T[128 * 68];
  const int tid = threadIdx.x;
  if (blockIdx.x < 256) {
    const int c = blockIdx.x;
    if (c == 0 && tid < 2) out[tid] = 0.0f;
    const float* b = xs + (size_t)c * 5120;
    for (int e = tid; e < 1024; e += 256) {
      float s = b[e] + b[1024 + e] + b[2048 + e] + b[3072 + e] + b[4096 + e];
      xbar[(size_t)c * 1024 + e] = s * 0.2f;
    }
  } else {
    const int kb = (blockIdx.x - 256) * 64;
#pragma unroll
    for (int s = 0; s < 8; ++s) {
      int idx = tid + s * 256;
      int kr = idx >> 5, n4 = idx & 31;
      float4 v = *(const float4*)(W + (size_t)(kb + kr) * 128 + n4 * 4);
      T[(n4 * 4 + 0) * 68 + kr] = (unsigned short)f2bf(v.x);
      T[(n4 * 4 + 1) * 68 + kr] = (unsigned short)f2bf(v.y);
      T[(n4 * 4 + 2) * 68 + kr] = (unsigned short)f2bf(v.z);
      T[(n4 * 4 + 3) * 68 + kr] = (unsigned short)f2bf(v.w);
    }
    __syncthreads();
#pragma unroll
    for (int s = 0; s < 8; ++s) {
      int idx = tid + s * 256;
      int n = idx >> 4, k4 = idx & 15;
      ushort4 o;
      o.x = T[n * 68 + k4 * 4 + 0];
      o.y = T[n * 68 + k4 * 4 + 1];
      o.z = T[n * 68 + k4 * 4 + 2];
      o.w = T[n * 68 + k4 * 4 + 3];
      *(ushort4*)(Wt + (size_t)n * 1024 + kb + k4 * 4) = o;
    }
  }
}

// ---------------- z = [xbar ; xq] @ W,  M=16640 N=128 K=1024 ----------------
// 260 blocks x 256 thr. Wave w: rows w*16..+15 x all 128 cols; BK=64, 16 tiles.
// LDS per buffer: A = 16 regions x 1KB (fp32), B = 16 regions x 1KB (bf16).
//   A region (w*4 + ks*2 + e): lane l=(qd,ln) -> row w*16+ln,
//       floats ks*32 + qd*8 + e*4 .. +4        (read: f32x4 @ base + l*16)
//   B region (t*2 + ks): lane l -> col t*16+ln, bf16 ks*32 + qd*8 .. +8
__global__ __launch_bounds__(256, 2) void k_gemm_z(
    const float* __restrict__ xbar, const float* __restrict__ xq,
    const unsigned short* __restrict__ Wt,
    unsigned short* __restrict__ zb, float* __restrict__ n2) {
  __shared__ __align__(16) char SM[2][32768];   // [buf][A 16KB | B 16KB]
  const int tid = threadIdx.x;
  const int w = tid >> 6, l = tid & 63, ln = l & 15, qd = l >> 4;
  const int mb = blockIdx.x * 64;
  const float* abase = (mb < 256) ? (xbar + (size_t)mb * 1024)
                                  : (xq + (size_t)(mb - 256) * 1024);
  // per-wave staging sources (4 A regions, 4 B regions)
  const float* as[4];
#pragma unroll
  for (int i = 0; i < 4; ++i)     // e=i&1, ks=i>>1
    as[i] = abase + (size_t)(w * 16 + ln) * 1024 + (i >> 1) * 32 + qd * 8 + (i & 1) * 4;
  const unsigned short* bs[4];    // i: t=2w+(i>>1), ks=i&1
  bs[0] = Wt + (size_t)(2 * w * 16 + ln) * 1024 + qd * 8;
  bs[1] = bs[0] + 32;
  bs[2] = bs[0] + 16 * 1024;
  bs[3] = bs[2] + 32;

  f32x4 acc[8] = {};

  // stage tile 0 -> buf 0
#pragma unroll
  for (int i = 0; i < 4; ++i)
    async16(as[i], SM[0] + (w * 4 + i) * 1024);
#pragma unroll
  for (int i = 0; i < 4; ++i)
    async16(bs[i], SM[0] + 16384 + (w * 4 + i) * 1024);

  for (int kt = 0; kt < 16; ++kt) {
    const int buf = kt & 1;
    __syncthreads();              // drains tile kt (issued last iter)
    if (kt < 15) {                // issue tile kt+1 -> other buffer
#pragma unroll
      for (int i = 0; i < 4; ++i)
        async16(as[i] + (kt + 1) * 64, SM[buf ^ 1] + (w * 4 + i) * 1024);
#pragma unroll
      for (int i = 0; i < 4; ++i)
        async16(bs[i] + (kt + 1) * 64, SM[buf ^ 1] + 16384 + (w * 4 + i) * 1024);
    }
    // compute tile kt from buf (LDS only; kt+1 loads fly meanwhile)
#pragma unroll
    for (int ks = 0; ks < 2; ++ks) {
      f32x4 alo = *(const f32x4*)(SM[buf] + (w * 4 + ks * 2 + 0) * 1024 + l * 16);
      f32x4 ahi = *(const f32x4*)(SM[buf] + (w * 4 + ks * 2 + 1) * 1024 + l * 16);
      s8v af = { f2bf(alo[0]), f2bf(alo[1]), f2bf(alo[2]), f2bf(alo[3]),
                 f2bf(ahi[0]), f2bf(ahi[1]), f2bf(ahi[2]), f2bf(ahi[3]) };
#pragma unroll
      for (int t = 0; t < 8; ++t) {
        s8v bf = *(const s8v*)(SM[buf] + 16384 + (t * 2 + ks) * 1024 + l * 16);
        acc[t] = __builtin_amdgcn_mfma_f32_16x16x32_bf16(af, bf, acc[t], 0, 0, 0);
      }
    }
  }
  // epilogue: bf16 z + full-row n2 (this block covers all 128 cols)
#pragma unroll
  for (int p = 0; p < 4; ++p) {
    const int grow = mb + w * 16 + qd * 4 + p;   // C/D: row = quad*4 + reg
    float sp = 0.0f;
#pragma unroll
    for (int t = 0; t < 8; ++t) {
      float v = acc[t][p];                       // col = t*16 + ln
      zb[(size_t)grow * 128 + t * 16 + ln] = (unsigned short)f2bf(v);
      sp += v * v;
    }
    sp += __shfl_xor(sp, 1);
    sp += __shfl_xor(sp, 2);
    sp += __shfl_xor(sp, 4);
    sp += __shfl_xor(sp, 8);
    if (ln == 0) n2[grow] = sp;
  }
}

// --------- fused d2 GEMM (64 queries x 256 protos) + per-class reduce ---------
__global__ __launch_bounds__(256, 1) void k_d2red(
    const unsigned short* __restrict__ zb, const float* __restrict__ n2,
    float* __restrict__ out) {
  __shared__ float Dt[256 * 65];          // Dt[j][q], stride 65 (bank-free)
  __shared__ float rv[256];
  __shared__ int   ri[256];
  __shared__ float rss[256];
  __shared__ float invn[64];
  __shared__ float sred[4];
  __shared__ float s_tc, s_aq2, s_corr;
  const int tid = threadIdx.x;
  const int c = blockIdx.x;
  const int w = tid >> 6, lane = tid & 63, ln = lane & 15, qd = lane >> 4;

  f32x4 acc[16] = {};
  const unsigned short* Az = zb + (size_t)(256 + c * 64 + w * 16 + ln) * 128;
  s8v af[4];
#pragma unroll
  for (int kt = 0; kt < 4; ++kt) af[kt] = *(const s8v*)(Az + kt * 32 + qd * 8);
#pragma unroll
  for (int t = 0; t < 16; ++t) {
    const unsigned short* Bz = zb + (size_t)(t * 16 + ln) * 128 + qd * 8;
    s8v bf0 = *(const s8v*)(Bz + 0 * 32);
    s8v bf1 = *(const s8v*)(Bz + 1 * 32);
    s8v bf2 = *(const s8v*)(Bz + 2 * 32);
    s8v bf3 = *(const s8v*)(Bz + 3 * 32);
    acc[t] = __builtin_amdgcn_mfma_f32_16x16x32_bf16(af[0], bf0, acc[t], 0, 0, 0);
    acc[t] = __builtin_amdgcn_mfma_f32_16x16x32_bf16(af[1], bf1, acc[t], 0, 0, 0);
    acc[t] = __builtin_amdgcn_mfma_f32_16x16x32_bf16(af[2], bf2, acc[t], 0, 0, 0);
    acc[t] = __builtin_amdgcn_mfma_f32_16x16x32_bf16(af[3], bf3, acc[t], 0, 0, 0);
  }
#pragma unroll
  for (int p = 0; p < 4; ++p) {
    int qloc = w * 16 + qd * 4 + p;
    float qn = n2[256 + c * 64 + qloc];
#pragma unroll
    for (int t = 0; t < 16; ++t) {
      int j = t * 16 + ln;
      Dt[j * 65 + qloc] = qn + n2[j] - 2.0f * acc[t][p];
    }
  }
  __syncthreads();

  {
    const int q = tid & 63, jb = (tid >> 6) * 64;
    float mn = 3.4e38f; int mi = 0; float ss = 0.0f;
    for (int jj = 0; jj < 64; ++jj) {
      int j = jb + jj;
      float f = Dt[j * 65 + q];
      ss += f * f;
      if (f < mn) { mn = f; mi = j; }
    }
    rv[tid] = mn; ri[tid] = mi; rss[tid] = ss;
  }
  __syncthreads();
  if (tid < 64) {
    float bm = rv[tid]; int bi = ri[tid]; float ss = rss[tid];
    for (int hh = 1; hh < 4; ++hh) {
      float v = rv[hh * 64 + tid];
      ss += rss[hh * 64 + tid];
      if (v < bm) { bm = v; bi = ri[hh * 64 + tid]; }
    }
    float col = Dt[c * 65 + tid];
    float loo2 = fmaxf(ss - col * col, 0.0f);
    float nrm = fmaxf(sqrtf(loo2), 1e-8f);
    float inv = 1.0f / nrm;
    invn[tid] = inv;
    float aq2 = loo2 * inv * inv;
    float corr = (bi == c) ? 1.0f : 0.0f;
    for (int m = 1; m < 64; m <<= 1) {
      aq2 += __shfl_xor(aq2, m);
      corr += __shfl_xor(corr, m);
    }
    if (tid == 0) { s_aq2 = aq2; s_corr = corr; }
  }
  __syncthreads();
  float t = 0.0f;
  for (int qq = 0; qq < 64; ++qq) t += Dt[tid * 65 + qq] * invn[qq];
  if (tid == c) s_tc = t;
  float t2 = t * t;
  for (int m = 1; m < 64; m <<= 1) t2 += __shfl_xor(t2, m);
  if ((tid & 63) == 0) sred[tid >> 6] = t2;
  __syncthreads();
  if (tid == 0) {
    float S2 = sred[0] + sred[1] + sred[2] + sred[3];
    float bs = 0.5f * (S2 - s_tc * s_tc - s_aq2);
    atomicAdd(&out[0], bs * (1.0f / 516096.0f));
    atomicAdd(&out[1], s_corr * (1.0f / 16384.0f));
  }
}

extern "C" void kernel_launch(void* const* d_in, const int* in_sizes, int n_in,
                              void* d_out, int out_size, void* d_ws, size_t ws_size,
                              hipStream_t stream) {
  const float* xs = (const float*)d_in[0];   // 256*5*1024
  const float* xq = (const float*)d_in[1];   // 256*64*1024
  const float* W  = (const float*)d_in[2];   // 1024*128
  float* out = (float*)d_out;

  float* ws = (float*)d_ws;
  float* xbar = ws;                                    // 262144 fp32 (1 MB)
  unsigned short* Wt = (unsigned short*)(xbar + 262144);          // 128K bf16
  unsigned short* zb = Wt + 131072;                               // 16640*128 bf16
  float* n2 = (float*)(zb + (size_t)16640 * 128);                 // 16640 fp32

  k_prep<<<dim3(272), dim3(256), 0, stream>>>(xs, W, xbar, Wt, out);
  k_gemm_z<<<dim3(260), dim3(256), 0, stream>>>(xbar, xq, Wt, zb, n2);
  k_d2red<<<dim3(256), dim3(256), 0, stream>>>(zb, n2, out);
}